// Round 4
// baseline (147.228 us; speedup 1.0000x reference)
//
#include <hip/hip_runtime.h>

#define DIM 256
#define NHEADS 8
#define HDIM 32

typedef _Float16 half8_t __attribute__((ext_vector_type(8)));
typedef _Float16 half4_t __attribute__((ext_vector_type(4)));
typedef float float4_t __attribute__((ext_vector_type(4)));

__device__ __forceinline__ float fast_exp2(float x) {
#if __has_builtin(__builtin_amdgcn_exp2f)
    return __builtin_amdgcn_exp2f(x);
#else
    return __expf(x * 0.6931471805599453f);
#endif
}

__device__ __forceinline__ void gload_lds16(const void* g, void* l) {
    __builtin_amdgcn_global_load_lds((const __attribute__((address_space(1))) void*)g,
                                     (__attribute__((address_space(3))) void*)l,
                                     16, 0, 0);
}

// ---------------------------------------------------------------------------
// prep: (a) x fp32 -> fp16 flat; (b) Wqkv [256,768] -> WqT [768,256] fp16;
//       (c) Wout [256,256] -> WoT [256,256] fp16 (transposed for B-frags).
// ---------------------------------------------------------------------------
__global__ __launch_bounds__(256) void prep(const float* __restrict__ x,
                                            const float* __restrict__ Wqkv,
                                            const float* __restrict__ Wout,
                                            _Float16* __restrict__ xh,
                                            _Float16* __restrict__ WqT,
                                            _Float16* __restrict__ WoT) {
    __shared__ float ts[32][33];
    const int bid = blockIdx.x, t = threadIdx.x;
    if (bid < 1024) {
        size_t idx = (size_t)bid * 2048 + (size_t)t * 8;
        float tmp[8];
        *reinterpret_cast<float4*>(tmp)     = *reinterpret_cast<const float4*>(x + idx);
        *reinterpret_cast<float4*>(tmp + 4) = *reinterpret_cast<const float4*>(x + idx + 4);
        half8_t h;
        #pragma unroll
        for (int j = 0; j < 8; ++j) h[j] = (_Float16)tmp[j];
        *reinterpret_cast<half8_t*>(xh + idx) = h;
    } else {
        const float* src; _Float16* dst; int K, N, kb, nb;
        if (bid < 1024 + 192) { int b2 = bid - 1024; src = Wqkv; dst = WqT; K = 256; N = 768; nb = b2 % 24; kb = b2 / 24; }
        else                  { int b3 = bid - 1216; src = Wout; dst = WoT; K = 256; N = 256; nb = b3 % 8;  kb = b3 / 8; }
        const int tx = t & 31, ty = t >> 5;
        #pragma unroll
        for (int i = 0; i < 4; ++i) {
            int k = kb * 32 + ty + i * 8;
            ts[ty + i * 8][tx] = src[(size_t)k * N + nb * 32 + tx];
        }
        __syncthreads();
        #pragma unroll
        for (int i = 0; i < 4; ++i) {
            int nl = ty + i * 8;
            dst[(size_t)(nb * 32 + nl) * K + kb * 32 + tx] = (_Float16)ts[tx][nl];
        }
    }
}

// ---------------------------------------------------------------------------
// fp16 MFMA GEMM, LDS-staged: C[M,N] = A[M,K] @ BT[N,K]^T.
// MROWS*32 x 128 tile, BK=32, 4 waves, global_load_lds 16B staging.
// VSPLIT (qkv gemm): tiles with n0>=512 are V -> written TRANSPOSED to
// VT[b][h][hd][token]; Q columns (n0<256) are pre-scaled by scale*log2(e)
// so attention can use exp2 directly.
// ---------------------------------------------------------------------------
template <bool OUT_HALF, bool VSPLIT, int MROWS>
__global__ __launch_bounds__(256) void gemm_h(const _Float16* __restrict__ A,
                                              const _Float16* __restrict__ BT,
                                              const float* __restrict__ bias,
                                              void* __restrict__ Cv,
                                              _Float16* __restrict__ VTo,
                                              int M, int N, int K, int ldc) {
    constexpr int BM = MROWS * 32;
    __shared__ alignas(16) _Float16 As[BM * 32];
    __shared__ alignas(16) _Float16 Bs[128 * 32];
    const int t = threadIdx.x, lane = t & 63, wave = t >> 6;
    const int l16 = lane & 15, quad = lane >> 4;
    const int m0 = blockIdx.y * BM, n0 = blockIdx.x * 128;
    const int wr = (wave >> 1) * (MROWS * 16), wc = (wave & 1) * 64;
    constexpr float QS = 0.17677669529663687f * 1.4426950408889634f;  // scale*log2e
    float4_t acc[MROWS][4];
    #pragma unroll
    for (int i = 0; i < MROWS; ++i)
        #pragma unroll
        for (int j = 0; j < 4; ++j) acc[i][j] = (float4_t){0.f, 0.f, 0.f, 0.f};

    const int srow = lane >> 2;        // 0..15 within 16-row chunk
    const int scol = (lane & 3) * 8;   // halves

    for (int k0 = 0; k0 < K; k0 += 32) {
        #pragma unroll
        for (int i = 0; i < MROWS / 2; ++i) {
            int chunk = i * 4 + wave;
            int r = chunk * 16 + srow;
            gload_lds16(A + (size_t)(m0 + r) * K + k0 + scol, As + chunk * 512);
        }
        #pragma unroll
        for (int i = 0; i < 2; ++i) {
            int chunk = i * 4 + wave;
            int r = chunk * 16 + srow;
            gload_lds16(BT + (size_t)(n0 + r) * K + k0 + scol, Bs + chunk * 512);
        }
        __syncthreads();
        half8_t af[MROWS], bf[4];
        #pragma unroll
        for (int i = 0; i < MROWS; ++i)
            af[i] = *reinterpret_cast<const half8_t*>(As + (wr + i * 16 + l16) * 32 + quad * 8);
        #pragma unroll
        for (int j = 0; j < 4; ++j)
            bf[j] = *reinterpret_cast<const half8_t*>(Bs + (wc + j * 16 + l16) * 32 + quad * 8);
        #pragma unroll
        for (int i = 0; i < MROWS; ++i)
            #pragma unroll
            for (int j = 0; j < 4; ++j)
                acc[i][j] = __builtin_amdgcn_mfma_f32_16x16x32_f16(af[i], bf[j], acc[i][j], 0, 0, 0);
        __syncthreads();
    }

    if (VSPLIT && n0 >= 512) {
        // V tile: write transposed VT[b][h][hd][token], 4 tokens per b64 store.
        const int bb = m0 >> 11;
        const int tok0 = (m0 & 2047) + wr;
        #pragma unroll
        for (int i = 0; i < MROWS; ++i)
            #pragma unroll
            for (int j = 0; j < 4; ++j) {
                int vcol = n0 + wc + j * 16 + l16 - 512;
                int hh = vcol >> 5, d = vcol & 31;
                half4_t p;
                #pragma unroll
                for (int r = 0; r < 4; ++r) p[r] = (_Float16)acc[i][j][r];
                *reinterpret_cast<half4_t*>(
                    VTo + ((size_t)(bb * NHEADS + hh) * HDIM + d) * 2048
                        + tok0 + i * 16 + quad * 4) = p;
            }
    } else {
        float bv[4] = {0.f, 0.f, 0.f, 0.f};
        if (bias != nullptr) {
            #pragma unroll
            for (int j = 0; j < 4; ++j) bv[j] = bias[n0 + wc + j * 16 + l16];
        }
        #pragma unroll
        for (int i = 0; i < MROWS; ++i)
            #pragma unroll
            for (int r = 0; r < 4; ++r) {
                int row = m0 + wr + i * 16 + quad * 4 + r;
                #pragma unroll
                for (int j = 0; j < 4; ++j) {
                    int col = n0 + wc + j * 16 + l16;
                    float v = acc[i][j][r] + bv[j];
                    if (VSPLIT && n0 < 256) v *= QS;  // pre-scale Q for exp2
                    if (OUT_HALF) ((_Float16*)Cv)[(size_t)row * ldc + col] = (_Float16)v;
                    else          ((float*)Cv)[(size_t)row * ldc + col] = v;
                }
            }
    }
}

// ---------------------------------------------------------------------------
// MFMA flash attention v9: occupancy-first.
//  - 32 q/wave, key-split x2 -> 16 iters/wave (minimal serial chain length).
//  - 1024 blocks = 4 blocks/CU; launch_bounds(256,4) + single-buffered K/V
//    (~95 VGPR) -> 16 waves/CU so TLP hides the load->MFMA->exp->LDS chain.
//  - XCD swizzle: 32 blocks sharing one (b,h)'s K/V land on one XCD's L2.
//  - ones-MFMA denominator, exp2 on pre-scaled Q, pkrtz packing (R1 diet).
// ---------------------------------------------------------------------------

#define LOADKV(P, k0)                                                              \
    do {                                                                           \
        const _Float16* kp_ = kbase + (size_t)(k0) * 512;                          \
        k##P##0 = *reinterpret_cast<const half8_t*>(kp_);                          \
        k##P##1 = *reinterpret_cast<const half8_t*>(kp_ + (size_t)16 * 512);       \
        k##P##2 = *reinterpret_cast<const half8_t*>(kp_ + (size_t)32 * 512);       \
        k##P##3 = *reinterpret_cast<const half8_t*>(kp_ + (size_t)48 * 512);       \
        const _Float16* vp_ = vbase + (k0);                                        \
        v##P##0 = *reinterpret_cast<const half8_t*>(vp_);                          \
        v##P##1 = *reinterpret_cast<const half8_t*>(vp_ + (size_t)16 * 2048);      \
        v##P##2 = *reinterpret_cast<const half8_t*>(vp_ + 32);                     \
        v##P##3 = *reinterpret_cast<const half8_t*>(vp_ + 32 + (size_t)16 * 2048); \
    } while (0)

#define EXPKB(KF, e0, e1)                                                          \
    do {                                                                           \
        float4_t st0 = __builtin_amdgcn_mfma_f32_16x16x32_f16(KF, qf0, z, 0, 0, 0);\
        float4_t st1 = __builtin_amdgcn_mfma_f32_16x16x32_f16(KF, qf1, z, 0, 0, 0);\
        auto lo0 = __builtin_amdgcn_cvt_pkrtz(fast_exp2(st0[0]), fast_exp2(st0[1]));\
        auto hi0 = __builtin_amdgcn_cvt_pkrtz(fast_exp2(st0[2]), fast_exp2(st0[3]));\
        e0 = (half4_t){(_Float16)lo0[0], (_Float16)lo0[1],                         \
                       (_Float16)hi0[0], (_Float16)hi0[1]};                        \
        auto lo1 = __builtin_amdgcn_cvt_pkrtz(fast_exp2(st1[0]), fast_exp2(st1[1]));\
        auto hi1 = __builtin_amdgcn_cvt_pkrtz(fast_exp2(st1[2]), fast_exp2(st1[3]));\
        e1 = (half4_t){(_Float16)lo1[0], (_Float16)lo1[1],                         \
                       (_Float16)hi1[0], (_Float16)hi1[1]};                        \
    } while (0)

#define PVCHUNK(ea0, ea1, eb0, eb1, VF0, VF1)                                      \
    do {                                                                           \
        *reinterpret_cast<half4_t*>(esw + l16 * 40 + quad * 4) = ea0;              \
        *reinterpret_cast<half4_t*>(esw + (16 + l16) * 40 + quad * 4) = ea1;       \
        *reinterpret_cast<half4_t*>(esw + l16 * 40 + 16 + quad * 4) = eb0;         \
        *reinterpret_cast<half4_t*>(esw + (16 + l16) * 40 + 16 + quad * 4) = eb1;  \
        half8_t ef0 = *reinterpret_cast<const half8_t*>(esw + l16 * 40 + quad * 8);\
        half8_t ef1 = *reinterpret_cast<const half8_t*>(esw + (16 + l16) * 40 + quad * 8);\
        num00 = __builtin_amdgcn_mfma_f32_16x16x32_f16(ef0, VF0, num00, 0, 0, 0);  \
        num01 = __builtin_amdgcn_mfma_f32_16x16x32_f16(ef0, VF1, num01, 0, 0, 0);  \
        dacc0 = __builtin_amdgcn_mfma_f32_16x16x32_f16(ef0, onef, dacc0, 0, 0, 0); \
        num10 = __builtin_amdgcn_mfma_f32_16x16x32_f16(ef1, VF0, num10, 0, 0, 0);  \
        num11 = __builtin_amdgcn_mfma_f32_16x16x32_f16(ef1, VF1, num11, 0, 0, 0);  \
        dacc1 = __builtin_amdgcn_mfma_f32_16x16x32_f16(ef1, onef, dacc1, 0, 0, 0); \
    } while (0)

#define STEP(P)                                                                    \
    do {                                                                           \
        half4_t e00, e01, e10, e11, e20, e21, e30, e31;                            \
        EXPKB(k##P##0, e00, e01);                                                  \
        EXPKB(k##P##1, e10, e11);                                                  \
        EXPKB(k##P##2, e20, e21);                                                  \
        EXPKB(k##P##3, e30, e31);                                                  \
        PVCHUNK(e00, e01, e10, e11, v##P##0, v##P##1);                             \
        PVCHUNK(e20, e21, e30, e31, v##P##2, v##P##3);                             \
    } while (0)

__global__ __launch_bounds__(256, 4) void attn_v9(const _Float16* __restrict__ qkh,
                                                  const _Float16* __restrict__ VT,
                                                  _Float16* __restrict__ NUM,
                                                  float* __restrict__ DEN) {
    __shared__ alignas(16) _Float16 es[4][32][40];
    // XCD swizzle (bijective, 1024 % 8 == 0): consecutive work shares an XCD L2.
    const int bid = ((blockIdx.x & 7) << 7) | (blockIdx.x >> 3);
    const int kh = bid & 1;
    const int qb = (bid >> 1) & 15;
    const int bh = bid >> 5;
    const int b = bh >> 3, h = bh & 7;
    const int t = threadIdx.x, lane = t & 63, wave = t >> 6;
    const int l16 = lane & 15, quad = lane >> 4;
    const int bN = b * 2048;
    const int q0w = qb * 128 + wave * 32;
    const int kbeg = kh * 1024;

    // Q fragments (B-operand of S^T): pre-scaled by scale*log2e, in regs.
    half8_t qf0, qf1;
    {
        const _Float16* qrow = qkh + (size_t)(bN + q0w + l16) * 512 + h * HDIM + quad * 8;
        qf0 = *reinterpret_cast<const half8_t*>(qrow);
        qf1 = *reinterpret_cast<const half8_t*>(qrow + (size_t)16 * 512);
    }

    const _Float16* kbase = qkh + (size_t)(bN + l16) * 512 + 256 + h * HDIM + quad * 8;
    const _Float16* vbase = VT + (size_t)bh * HDIM * 2048 + (size_t)l16 * 2048 + quad * 8;

    float4_t num00 = {0.f, 0.f, 0.f, 0.f}, num01 = {0.f, 0.f, 0.f, 0.f};
    float4_t num10 = {0.f, 0.f, 0.f, 0.f}, num11 = {0.f, 0.f, 0.f, 0.f};
    float4_t dacc0 = {0.f, 0.f, 0.f, 0.f}, dacc1 = {0.f, 0.f, 0.f, 0.f};

    half8_t onef;
    #pragma unroll
    for (int j = 0; j < 8; ++j) onef[j] = (_Float16)1.0f;

    _Float16* esw = &es[wave][0][0];
    const float4_t z = {0.f, 0.f, 0.f, 0.f};

    half8_t kA0, kA1, kA2, kA3, vA0, vA1, vA2, vA3;
    for (int k0 = kbeg; k0 < kbeg + 1024; k0 += 64) {
        LOADKV(A, k0);
        STEP(A);
    }

    // Store partial numerator (fp16, unnormalized) and partial denom (fp32).
    _Float16* ob = NUM + (size_t)kh * 2097152 + (size_t)(bN + q0w) * DIM + h * HDIM;
    #pragma unroll
    for (int r = 0; r < 4; ++r) {
        size_t ro0 = (size_t)(quad * 4 + r) * DIM;
        size_t ro1 = (size_t)(16 + quad * 4 + r) * DIM;
        ob[ro0 + l16]      = (_Float16)num00[r];
        ob[ro0 + 16 + l16] = (_Float16)num01[r];
        ob[ro1 + l16]      = (_Float16)num10[r];
        ob[ro1 + 16 + l16] = (_Float16)num11[r];
    }
    // dacc[g][r] = denom for q = g*16 + quad*4 + r (replicated over l16).
    if (l16 == 0) {
        #pragma unroll
        for (int r = 0; r < 4; ++r) {
            DEN[kh * 65536 + bh * 2048 + q0w + quad * 4 + r]      = dacc0[r];
            DEN[kh * 65536 + bh * 2048 + q0w + 16 + quad * 4 + r] = dacc1[r];
        }
    }
}

// ---------------------------------------------------------------------------
// combine: attnh = (NUM0 + NUM1) * rcp(DEN0 + DEN1 + 1e-6), elementwise fp16.
// ---------------------------------------------------------------------------
__global__ __launch_bounds__(256) void combine(const _Float16* __restrict__ NUM,
                                               const float* __restrict__ DEN,
                                               _Float16* __restrict__ attnh) {
    const size_t idx = ((size_t)blockIdx.x * 256 + threadIdx.x) * 8;
    const int row = (int)(idx >> 8);
    const int c = (int)(idx & 255);
    const int b = row >> 11, tok = row & 2047, h = c >> 5;
    const int di = (b * 8 + h) * 2048 + tok;
    float rcp = 1.0f / (DEN[di] + DEN[di + 65536] + 1e-6f);
    half8_t n0 = *reinterpret_cast<const half8_t*>(NUM + idx);
    half8_t n1 = *reinterpret_cast<const half8_t*>(NUM + idx + 2097152);
    *reinterpret_cast<half8_t*>(attnh + idx) = (n0 + n1) * (_Float16)rcp;
}

extern "C" void kernel_launch(void* const* d_in, const int* in_sizes, int n_in,
                              void* d_out, int out_size, void* d_ws, size_t ws_size,
                              hipStream_t stream) {
    const float* x    = (const float*)d_in[0];
    const float* Wqkv = (const float*)d_in[1];
    const float* Wout = (const float*)d_in[2];
    const float* bout = (const float*)d_in[3];
    float* out = (float*)d_out;
    const int M = 8192;

    _Float16* xh    = (_Float16*)d_ws;                 // [8192,256]
    _Float16* WqT   = xh + (size_t)M * DIM;            // [768,256]
    _Float16* WoT   = WqT + 768 * 256;                 // [256,256]
    _Float16* qkh   = WoT + 256 * 256;                 // [8192,512]  (Q|K)
    _Float16* vt    = qkh + (size_t)M * 512;           // [4][8][32][2048] V^T
    _Float16* NUM   = vt + (size_t)32 * HDIM * 2048;   // [2][8192,256] partials
    float*    DEN   = (float*)(NUM + (size_t)2 * M * DIM);  // [2][65536]
    _Float16* attnh = (_Float16*)(DEN + 2 * 65536);    // [8192,256]

    hipLaunchKernelGGL(prep, dim3(1280), dim3(256), 0, stream, x, Wqkv, Wout, xh, WqT, WoT);
    // qkv GEMM: Q (scaled by scale*log2e), K -> qkh (ldc 512); V -> vt transposed.
    // 64-row M-tiles: 768 blocks = 3 exact CU-rounds.
    hipLaunchKernelGGL((gemm_h<true, true, 2>), dim3(6, 128), dim3(256), 0, stream,
                       xh, WqT, (const float*)nullptr, (void*)qkh, vt, M, 768, DIM, 512);
    // attention: 1024 blocks (4/CU, 16 waves/CU), key-split x2 -> partials.
    hipLaunchKernelGGL(attn_v9, dim3(1024), dim3(256), 0, stream, qkh, vt, NUM, DEN);
    // combine partials -> attnh
    hipLaunchKernelGGL(combine, dim3(1024), dim3(256), 0, stream, NUM, DEN, attnh);
    // out = attnh @ Wout + bout (fp32 out): 64-row M-tiles -> 256 balanced blocks.
    hipLaunchKernelGGL((gemm_h<false, false, 2>), dim3(2, 128), dim3(256), 0, stream,
                       attnh, WoT, bout, (void*)out, (_Float16*)nullptr, M, DIM, DIM, DIM);
}

// Round 5
// 146.759 us; speedup vs baseline: 1.0032x; 1.0032x over previous
//
#include <hip/hip_runtime.h>

#define DIM 256
#define NHEADS 8
#define HDIM 32

typedef _Float16 half8_t __attribute__((ext_vector_type(8)));
typedef _Float16 half4_t __attribute__((ext_vector_type(4)));
typedef float float4_t __attribute__((ext_vector_type(4)));

__device__ __forceinline__ float fast_exp2(float x) {
#if __has_builtin(__builtin_amdgcn_exp2f)
    return __builtin_amdgcn_exp2f(x);
#else
    return __expf(x * 0.6931471805599453f);
#endif
}

__device__ __forceinline__ void gload_lds16(const void* g, void* l) {
    __builtin_amdgcn_global_load_lds((const __attribute__((address_space(1))) void*)g,
                                     (__attribute__((address_space(3))) void*)l,
                                     16, 0, 0);
}

// ---------------------------------------------------------------------------
// prep: (a) x fp32 -> fp16 flat; (b) Wqkv [256,768] -> WqT [768,256] fp16;
//       (c) Wout [256,256] -> WoT [256,256] fp16 (transposed for B-frags).
// ---------------------------------------------------------------------------
__global__ __launch_bounds__(256) void prep(const float* __restrict__ x,
                                            const float* __restrict__ Wqkv,
                                            const float* __restrict__ Wout,
                                            _Float16* __restrict__ xh,
                                            _Float16* __restrict__ WqT,
                                            _Float16* __restrict__ WoT) {
    __shared__ float ts[32][33];
    const int bid = blockIdx.x, t = threadIdx.x;
    if (bid < 1024) {
        size_t idx = (size_t)bid * 2048 + (size_t)t * 8;
        float tmp[8];
        *reinterpret_cast<float4*>(tmp)     = *reinterpret_cast<const float4*>(x + idx);
        *reinterpret_cast<float4*>(tmp + 4) = *reinterpret_cast<const float4*>(x + idx + 4);
        half8_t h;
        #pragma unroll
        for (int j = 0; j < 8; ++j) h[j] = (_Float16)tmp[j];
        *reinterpret_cast<half8_t*>(xh + idx) = h;
    } else {
        const float* src; _Float16* dst; int K, N, kb, nb;
        if (bid < 1024 + 192) { int b2 = bid - 1024; src = Wqkv; dst = WqT; K = 256; N = 768; nb = b2 % 24; kb = b2 / 24; }
        else                  { int b3 = bid - 1216; src = Wout; dst = WoT; K = 256; N = 256; nb = b3 % 8;  kb = b3 / 8; }
        const int tx = t & 31, ty = t >> 5;
        #pragma unroll
        for (int i = 0; i < 4; ++i) {
            int k = kb * 32 + ty + i * 8;
            ts[ty + i * 8][tx] = src[(size_t)k * N + nb * 32 + tx];
        }
        __syncthreads();
        #pragma unroll
        for (int i = 0; i < 4; ++i) {
            int nl = ty + i * 8;
            dst[(size_t)(nb * 32 + nl) * K + kb * 32 + tx] = (_Float16)ts[tx][nl];
        }
    }
}

// ---------------------------------------------------------------------------
// fp16 MFMA GEMM, LDS-staged: C[M,N] = A[M,K] @ BT[N,K]^T.
// MROWS*32 x 128 tile, BK=32, 4 waves, global_load_lds 16B staging.
// VSPLIT (qkv gemm): tiles with n0>=512 are V -> written TRANSPOSED to
// VT[b][h][hd][token]; Q columns (n0<256) are pre-scaled by scale*log2(e)
// so attention can use exp2 directly.
// ---------------------------------------------------------------------------
template <bool OUT_HALF, bool VSPLIT, int MROWS>
__global__ __launch_bounds__(256) void gemm_h(const _Float16* __restrict__ A,
                                              const _Float16* __restrict__ BT,
                                              const float* __restrict__ bias,
                                              void* __restrict__ Cv,
                                              _Float16* __restrict__ VTo,
                                              int M, int N, int K, int ldc) {
    constexpr int BM = MROWS * 32;
    __shared__ alignas(16) _Float16 As[BM * 32];
    __shared__ alignas(16) _Float16 Bs[128 * 32];
    const int t = threadIdx.x, lane = t & 63, wave = t >> 6;
    const int l16 = lane & 15, quad = lane >> 4;
    const int m0 = blockIdx.y * BM, n0 = blockIdx.x * 128;
    const int wr = (wave >> 1) * (MROWS * 16), wc = (wave & 1) * 64;
    constexpr float QS = 0.17677669529663687f * 1.4426950408889634f;  // scale*log2e
    float4_t acc[MROWS][4];
    #pragma unroll
    for (int i = 0; i < MROWS; ++i)
        #pragma unroll
        for (int j = 0; j < 4; ++j) acc[i][j] = (float4_t){0.f, 0.f, 0.f, 0.f};

    const int srow = lane >> 2;        // 0..15 within 16-row chunk
    const int scol = (lane & 3) * 8;   // halves

    for (int k0 = 0; k0 < K; k0 += 32) {
        #pragma unroll
        for (int i = 0; i < MROWS / 2; ++i) {
            int chunk = i * 4 + wave;
            int r = chunk * 16 + srow;
            gload_lds16(A + (size_t)(m0 + r) * K + k0 + scol, As + chunk * 512);
        }
        #pragma unroll
        for (int i = 0; i < 2; ++i) {
            int chunk = i * 4 + wave;
            int r = chunk * 16 + srow;
            gload_lds16(BT + (size_t)(n0 + r) * K + k0 + scol, Bs + chunk * 512);
        }
        __syncthreads();
        half8_t af[MROWS], bf[4];
        #pragma unroll
        for (int i = 0; i < MROWS; ++i)
            af[i] = *reinterpret_cast<const half8_t*>(As + (wr + i * 16 + l16) * 32 + quad * 8);
        #pragma unroll
        for (int j = 0; j < 4; ++j)
            bf[j] = *reinterpret_cast<const half8_t*>(Bs + (wc + j * 16 + l16) * 32 + quad * 8);
        #pragma unroll
        for (int i = 0; i < MROWS; ++i)
            #pragma unroll
            for (int j = 0; j < 4; ++j)
                acc[i][j] = __builtin_amdgcn_mfma_f32_16x16x32_f16(af[i], bf[j], acc[i][j], 0, 0, 0);
        __syncthreads();
    }

    if (VSPLIT && n0 >= 512) {
        // V tile: write transposed VT[b][h][hd][token], 4 tokens per b64 store.
        const int bb = m0 >> 11;
        const int tok0 = (m0 & 2047) + wr;
        #pragma unroll
        for (int i = 0; i < MROWS; ++i)
            #pragma unroll
            for (int j = 0; j < 4; ++j) {
                int vcol = n0 + wc + j * 16 + l16 - 512;
                int hh = vcol >> 5, d = vcol & 31;
                half4_t p;
                #pragma unroll
                for (int r = 0; r < 4; ++r) p[r] = (_Float16)acc[i][j][r];
                *reinterpret_cast<half4_t*>(
                    VTo + ((size_t)(bb * NHEADS + hh) * HDIM + d) * 2048
                        + tok0 + i * 16 + quad * 4) = p;
            }
    } else {
        float bv[4] = {0.f, 0.f, 0.f, 0.f};
        if (bias != nullptr) {
            #pragma unroll
            for (int j = 0; j < 4; ++j) bv[j] = bias[n0 + wc + j * 16 + l16];
        }
        #pragma unroll
        for (int i = 0; i < MROWS; ++i)
            #pragma unroll
            for (int r = 0; r < 4; ++r) {
                int row = m0 + wr + i * 16 + quad * 4 + r;
                #pragma unroll
                for (int j = 0; j < 4; ++j) {
                    int col = n0 + wc + j * 16 + l16;
                    float v = acc[i][j][r] + bv[j];
                    if (VSPLIT && n0 < 256) v *= QS;  // pre-scale Q for exp2
                    if (OUT_HALF) ((_Float16*)Cv)[(size_t)row * ldc + col] = (_Float16)v;
                    else          ((float*)Cv)[(size_t)row * ldc + col] = v;
                }
            }
    }
}

// ---------------------------------------------------------------------------
// MFMA flash attention v10: short chain + real prefetch + VGPR headroom.
//  - 32 q/wave, key-split x2 -> 16 iters/wave; 1024 blocks.
//  - launch_bounds(256,3): VGPR cap 168 -> both ping-pong banks (64 regs)
//    stay resident; 12 waves/CU. (v9's (256,4) forced VGPR=48 -> compiler
//    sank all K/V loads into the serial chain: 9.7k cyc/iter, 65us.)
//  - sched_barrier(0) after each prefetch LOADKV pins load issue BEFORE the
//    consuming STEP -> global latency overlaps previous step's exp/LDS/MFMA.
//  - ones-MFMA denominator, exp2 on pre-scaled Q, pkrtz packing (R1 diet).
// ---------------------------------------------------------------------------

#define LOADKV(P, k0)                                                              \
    do {                                                                           \
        const _Float16* kp_ = kbase + (size_t)(k0) * 512;                          \
        k##P##0 = *reinterpret_cast<const half8_t*>(kp_);                          \
        k##P##1 = *reinterpret_cast<const half8_t*>(kp_ + (size_t)16 * 512);       \
        k##P##2 = *reinterpret_cast<const half8_t*>(kp_ + (size_t)32 * 512);       \
        k##P##3 = *reinterpret_cast<const half8_t*>(kp_ + (size_t)48 * 512);       \
        const _Float16* vp_ = vbase + (k0);                                        \
        v##P##0 = *reinterpret_cast<const half8_t*>(vp_);                          \
        v##P##1 = *reinterpret_cast<const half8_t*>(vp_ + (size_t)16 * 2048);      \
        v##P##2 = *reinterpret_cast<const half8_t*>(vp_ + 32);                     \
        v##P##3 = *reinterpret_cast<const half8_t*>(vp_ + 32 + (size_t)16 * 2048); \
    } while (0)

#define EXPKB(KF, e0, e1)                                                          \
    do {                                                                           \
        float4_t st0 = __builtin_amdgcn_mfma_f32_16x16x32_f16(KF, qf0, z, 0, 0, 0);\
        float4_t st1 = __builtin_amdgcn_mfma_f32_16x16x32_f16(KF, qf1, z, 0, 0, 0);\
        auto lo0 = __builtin_amdgcn_cvt_pkrtz(fast_exp2(st0[0]), fast_exp2(st0[1]));\
        auto hi0 = __builtin_amdgcn_cvt_pkrtz(fast_exp2(st0[2]), fast_exp2(st0[3]));\
        e0 = (half4_t){(_Float16)lo0[0], (_Float16)lo0[1],                         \
                       (_Float16)hi0[0], (_Float16)hi0[1]};                        \
        auto lo1 = __builtin_amdgcn_cvt_pkrtz(fast_exp2(st1[0]), fast_exp2(st1[1]));\
        auto hi1 = __builtin_amdgcn_cvt_pkrtz(fast_exp2(st1[2]), fast_exp2(st1[3]));\
        e1 = (half4_t){(_Float16)lo1[0], (_Float16)lo1[1],                         \
                       (_Float16)hi1[0], (_Float16)hi1[1]};                        \
    } while (0)

#define PVCHUNK(ea0, ea1, eb0, eb1, VF0, VF1)                                      \
    do {                                                                           \
        *reinterpret_cast<half4_t*>(esw + l16 * 40 + quad * 4) = ea0;              \
        *reinterpret_cast<half4_t*>(esw + (16 + l16) * 40 + quad * 4) = ea1;       \
        *reinterpret_cast<half4_t*>(esw + l16 * 40 + 16 + quad * 4) = eb0;         \
        *reinterpret_cast<half4_t*>(esw + (16 + l16) * 40 + 16 + quad * 4) = eb1;  \
        half8_t ef0 = *reinterpret_cast<const half8_t*>(esw + l16 * 40 + quad * 8);\
        half8_t ef1 = *reinterpret_cast<const half8_t*>(esw + (16 + l16) * 40 + quad * 8);\
        num00 = __builtin_amdgcn_mfma_f32_16x16x32_f16(ef0, VF0, num00, 0, 0, 0);  \
        num01 = __builtin_amdgcn_mfma_f32_16x16x32_f16(ef0, VF1, num01, 0, 0, 0);  \
        dacc0 = __builtin_amdgcn_mfma_f32_16x16x32_f16(ef0, onef, dacc0, 0, 0, 0); \
        num10 = __builtin_amdgcn_mfma_f32_16x16x32_f16(ef1, VF0, num10, 0, 0, 0);  \
        num11 = __builtin_amdgcn_mfma_f32_16x16x32_f16(ef1, VF1, num11, 0, 0, 0);  \
        dacc1 = __builtin_amdgcn_mfma_f32_16x16x32_f16(ef1, onef, dacc1, 0, 0, 0); \
    } while (0)

#define STEP(P)                                                                    \
    do {                                                                           \
        half4_t e00, e01, e10, e11, e20, e21, e30, e31;                            \
        EXPKB(k##P##0, e00, e01);                                                  \
        EXPKB(k##P##1, e10, e11);                                                  \
        EXPKB(k##P##2, e20, e21);                                                  \
        EXPKB(k##P##3, e30, e31);                                                  \
        PVCHUNK(e00, e01, e10, e11, v##P##0, v##P##1);                             \
        PVCHUNK(e20, e21, e30, e31, v##P##2, v##P##3);                             \
    } while (0)

__global__ __launch_bounds__(256, 3) void attn_v10(const _Float16* __restrict__ qkh,
                                                   const _Float16* __restrict__ VT,
                                                   _Float16* __restrict__ NUM,
                                                   float* __restrict__ DEN) {
    __shared__ alignas(16) _Float16 es[4][32][40];
    // XCD swizzle (bijective, 1024 % 8 == 0): consecutive work shares an XCD L2.
    const int bid = ((blockIdx.x & 7) << 7) | (blockIdx.x >> 3);
    const int kh = bid & 1;
    const int qb = (bid >> 1) & 15;
    const int bh = bid >> 5;
    const int b = bh >> 3, h = bh & 7;
    const int t = threadIdx.x, lane = t & 63, wave = t >> 6;
    const int l16 = lane & 15, quad = lane >> 4;
    const int bN = b * 2048;
    const int q0w = qb * 128 + wave * 32;
    const int kbeg = kh * 1024;

    // Q fragments (B-operand of S^T): pre-scaled by scale*log2e, in regs.
    half8_t qf0, qf1;
    {
        const _Float16* qrow = qkh + (size_t)(bN + q0w + l16) * 512 + h * HDIM + quad * 8;
        qf0 = *reinterpret_cast<const half8_t*>(qrow);
        qf1 = *reinterpret_cast<const half8_t*>(qrow + (size_t)16 * 512);
    }

    const _Float16* kbase = qkh + (size_t)(bN + l16) * 512 + 256 + h * HDIM + quad * 8;
    const _Float16* vbase = VT + (size_t)bh * HDIM * 2048 + (size_t)l16 * 2048 + quad * 8;

    float4_t num00 = {0.f, 0.f, 0.f, 0.f}, num01 = {0.f, 0.f, 0.f, 0.f};
    float4_t num10 = {0.f, 0.f, 0.f, 0.f}, num11 = {0.f, 0.f, 0.f, 0.f};
    float4_t dacc0 = {0.f, 0.f, 0.f, 0.f}, dacc1 = {0.f, 0.f, 0.f, 0.f};

    half8_t onef;
    #pragma unroll
    for (int j = 0; j < 8; ++j) onef[j] = (_Float16)1.0f;

    _Float16* esw = &es[wave][0][0];
    const float4_t z = {0.f, 0.f, 0.f, 0.f};

    // Two-bank register ping-pong; sched_barrier pins prefetch issue early.
    half8_t kA0, kA1, kA2, kA3, vA0, vA1, vA2, vA3;
    half8_t kB0, kB1, kB2, kB3, vB0, vB1, vB2, vB3;
    LOADKV(A, kbeg);
    __builtin_amdgcn_sched_barrier(0);
    #pragma unroll 2
    for (int k0 = kbeg; k0 < kbeg + 1024; k0 += 128) {
        LOADKV(B, k0 + 64);
        __builtin_amdgcn_sched_barrier(0);
        STEP(A);
        if (k0 + 128 < kbeg + 1024) {
            LOADKV(A, k0 + 128);
            __builtin_amdgcn_sched_barrier(0);
        }
        STEP(B);
    }

    // Store partial numerator (fp16, unnormalized) and partial denom (fp32).
    _Float16* ob = NUM + (size_t)kh * 2097152 + (size_t)(bN + q0w) * DIM + h * HDIM;
    #pragma unroll
    for (int r = 0; r < 4; ++r) {
        size_t ro0 = (size_t)(quad * 4 + r) * DIM;
        size_t ro1 = (size_t)(16 + quad * 4 + r) * DIM;
        ob[ro0 + l16]      = (_Float16)num00[r];
        ob[ro0 + 16 + l16] = (_Float16)num01[r];
        ob[ro1 + l16]      = (_Float16)num10[r];
        ob[ro1 + 16 + l16] = (_Float16)num11[r];
    }
    // dacc[g][r] = denom for q = g*16 + quad*4 + r (replicated over l16).
    if (l16 == 0) {
        #pragma unroll
        for (int r = 0; r < 4; ++r) {
            DEN[kh * 65536 + bh * 2048 + q0w + quad * 4 + r]      = dacc0[r];
            DEN[kh * 65536 + bh * 2048 + q0w + 16 + quad * 4 + r] = dacc1[r];
        }
    }
}

// ---------------------------------------------------------------------------
// combine: attnh = (NUM0 + NUM1) * rcp(DEN0 + DEN1 + 1e-6), elementwise fp16.
// ---------------------------------------------------------------------------
__global__ __launch_bounds__(256) void combine(const _Float16* __restrict__ NUM,
                                               const float* __restrict__ DEN,
                                               _Float16* __restrict__ attnh) {
    const size_t idx = ((size_t)blockIdx.x * 256 + threadIdx.x) * 8;
    const int row = (int)(idx >> 8);
    const int c = (int)(idx & 255);
    const int b = row >> 11, tok = row & 2047, h = c >> 5;
    const int di = (b * 8 + h) * 2048 + tok;
    float rcp = 1.0f / (DEN[di] + DEN[di + 65536] + 1e-6f);
    half8_t n0 = *reinterpret_cast<const half8_t*>(NUM + idx);
    half8_t n1 = *reinterpret_cast<const half8_t*>(NUM + idx + 2097152);
    *reinterpret_cast<half8_t*>(attnh + idx) = (n0 + n1) * (_Float16)rcp;
}

extern "C" void kernel_launch(void* const* d_in, const int* in_sizes, int n_in,
                              void* d_out, int out_size, void* d_ws, size_t ws_size,
                              hipStream_t stream) {
    const float* x    = (const float*)d_in[0];
    const float* Wqkv = (const float*)d_in[1];
    const float* Wout = (const float*)d_in[2];
    const float* bout = (const float*)d_in[3];
    float* out = (float*)d_out;
    const int M = 8192;

    _Float16* xh    = (_Float16*)d_ws;                 // [8192,256]
    _Float16* WqT   = xh + (size_t)M * DIM;            // [768,256]
    _Float16* WoT   = WqT + 768 * 256;                 // [256,256]
    _Float16* qkh   = WoT + 256 * 256;                 // [8192,512]  (Q|K)
    _Float16* vt    = qkh + (size_t)M * 512;           // [4][8][32][2048] V^T
    _Float16* NUM   = vt + (size_t)32 * HDIM * 2048;   // [2][8192,256] partials
    float*    DEN   = (float*)(NUM + (size_t)2 * M * DIM);  // [2][65536]
    _Float16* attnh = (_Float16*)(DEN + 2 * 65536);    // [8192,256]

    hipLaunchKernelGGL(prep, dim3(1280), dim3(256), 0, stream, x, Wqkv, Wout, xh, WqT, WoT);
    // qkv GEMM: Q (scaled by scale*log2e), K -> qkh (ldc 512); V -> vt transposed.
    hipLaunchKernelGGL((gemm_h<true, true, 2>), dim3(6, 128), dim3(256), 0, stream,
                       xh, WqT, (const float*)nullptr, (void*)qkh, vt, M, 768, DIM, 512);
    // attention: 1024 blocks, key-split x2 -> partials; prefetch ping-pong.
    hipLaunchKernelGGL(attn_v10, dim3(1024), dim3(256), 0, stream, qkh, vt, NUM, DEN);
    // combine partials -> attnh
    hipLaunchKernelGGL(combine, dim3(1024), dim3(256), 0, stream, NUM, DEN, attnh);
    // out = attnh @ Wout + bout (fp32 out): 64-row M-tiles -> 256 balanced blocks.
    hipLaunchKernelGGL((gemm_h<false, false, 2>), dim3(2, 128), dim3(256), 0, stream,
                       attnh, WoT, bout, (void*)out, (_Float16*)nullptr, M, DIM, DIM, DIM);
}

// Round 6
// 120.780 us; speedup vs baseline: 1.2190x; 1.2151x over previous
//
#include <hip/hip_runtime.h>

#define DIM 256
#define NHEADS 8
#define HDIM 32

typedef _Float16 half8_t __attribute__((ext_vector_type(8)));
typedef _Float16 half4_t __attribute__((ext_vector_type(4)));
typedef float float4_t __attribute__((ext_vector_type(4)));

__device__ __forceinline__ float fast_exp2(float x) {
#if __has_builtin(__builtin_amdgcn_exp2f)
    return __builtin_amdgcn_exp2f(x);
#else
    return __expf(x * 0.6931471805599453f);
#endif
}

__device__ __forceinline__ void gload_lds16(const void* g, void* l) {
    __builtin_amdgcn_global_load_lds((const __attribute__((address_space(1))) void*)g,
                                     (__attribute__((address_space(3))) void*)l,
                                     16, 0, 0);
}

// ---------------------------------------------------------------------------
// prep: (a) x fp32 -> fp16 flat; (b) Wqkv [256,768] -> WqT [768,256] fp16;
//       (c) Wout [256,256] -> WoT [256,256] fp16 (transposed for B-frags).
// ---------------------------------------------------------------------------
__global__ __launch_bounds__(256) void prep(const float* __restrict__ x,
                                            const float* __restrict__ Wqkv,
                                            const float* __restrict__ Wout,
                                            _Float16* __restrict__ xh,
                                            _Float16* __restrict__ WqT,
                                            _Float16* __restrict__ WoT) {
    __shared__ float ts[32][33];
    const int bid = blockIdx.x, t = threadIdx.x;
    if (bid < 1024) {
        size_t idx = (size_t)bid * 2048 + (size_t)t * 8;
        float tmp[8];
        *reinterpret_cast<float4*>(tmp)     = *reinterpret_cast<const float4*>(x + idx);
        *reinterpret_cast<float4*>(tmp + 4) = *reinterpret_cast<const float4*>(x + idx + 4);
        half8_t h;
        #pragma unroll
        for (int j = 0; j < 8; ++j) h[j] = (_Float16)tmp[j];
        *reinterpret_cast<half8_t*>(xh + idx) = h;
    } else {
        const float* src; _Float16* dst; int K, N, kb, nb;
        if (bid < 1024 + 192) { int b2 = bid - 1024; src = Wqkv; dst = WqT; K = 256; N = 768; nb = b2 % 24; kb = b2 / 24; }
        else                  { int b3 = bid - 1216; src = Wout; dst = WoT; K = 256; N = 256; nb = b3 % 8;  kb = b3 / 8; }
        const int tx = t & 31, ty = t >> 5;
        #pragma unroll
        for (int i = 0; i < 4; ++i) {
            int k = kb * 32 + ty + i * 8;
            ts[ty + i * 8][tx] = src[(size_t)k * N + nb * 32 + tx];
        }
        __syncthreads();
        #pragma unroll
        for (int i = 0; i < 4; ++i) {
            int nl = ty + i * 8;
            dst[(size_t)(nb * 32 + nl) * K + kb * 32 + tx] = (_Float16)ts[tx][nl];
        }
    }
}

// ---------------------------------------------------------------------------
// fp16 MFMA GEMM, LDS-staged: C[M,N] = A[M,K] @ BT[N,K]^T.
// MROWS*32 x 128 tile, BK=32, 4 waves, global_load_lds 16B staging.
// VSPLIT (qkv gemm): tiles with n0>=512 are V -> written TRANSPOSED to
// VT[b][h][hd][token]; Q columns (n0<256) are pre-scaled by scale*log2(e)
// so attention can use exp2 directly.
// ---------------------------------------------------------------------------
template <bool OUT_HALF, bool VSPLIT, int MROWS>
__global__ __launch_bounds__(256) void gemm_h(const _Float16* __restrict__ A,
                                              const _Float16* __restrict__ BT,
                                              const float* __restrict__ bias,
                                              void* __restrict__ Cv,
                                              _Float16* __restrict__ VTo,
                                              int M, int N, int K, int ldc) {
    constexpr int BM = MROWS * 32;
    __shared__ alignas(16) _Float16 As[BM * 32];
    __shared__ alignas(16) _Float16 Bs[128 * 32];
    const int t = threadIdx.x, lane = t & 63, wave = t >> 6;
    const int l16 = lane & 15, quad = lane >> 4;
    const int m0 = blockIdx.y * BM, n0 = blockIdx.x * 128;
    const int wr = (wave >> 1) * (MROWS * 16), wc = (wave & 1) * 64;
    constexpr float QS = 0.17677669529663687f * 1.4426950408889634f;  // scale*log2e
    float4_t acc[MROWS][4];
    #pragma unroll
    for (int i = 0; i < MROWS; ++i)
        #pragma unroll
        for (int j = 0; j < 4; ++j) acc[i][j] = (float4_t){0.f, 0.f, 0.f, 0.f};

    const int srow = lane >> 2;        // 0..15 within 16-row chunk
    const int scol = (lane & 3) * 8;   // halves

    for (int k0 = 0; k0 < K; k0 += 32) {
        #pragma unroll
        for (int i = 0; i < MROWS / 2; ++i) {
            int chunk = i * 4 + wave;
            int r = chunk * 16 + srow;
            gload_lds16(A + (size_t)(m0 + r) * K + k0 + scol, As + chunk * 512);
        }
        #pragma unroll
        for (int i = 0; i < 2; ++i) {
            int chunk = i * 4 + wave;
            int r = chunk * 16 + srow;
            gload_lds16(BT + (size_t)(n0 + r) * K + k0 + scol, Bs + chunk * 512);
        }
        __syncthreads();
        half8_t af[MROWS], bf[4];
        #pragma unroll
        for (int i = 0; i < MROWS; ++i)
            af[i] = *reinterpret_cast<const half8_t*>(As + (wr + i * 16 + l16) * 32 + quad * 8);
        #pragma unroll
        for (int j = 0; j < 4; ++j)
            bf[j] = *reinterpret_cast<const half8_t*>(Bs + (wc + j * 16 + l16) * 32 + quad * 8);
        #pragma unroll
        for (int i = 0; i < MROWS; ++i)
            #pragma unroll
            for (int j = 0; j < 4; ++j)
                acc[i][j] = __builtin_amdgcn_mfma_f32_16x16x32_f16(af[i], bf[j], acc[i][j], 0, 0, 0);
        __syncthreads();
    }

    if (VSPLIT && n0 >= 512) {
        // V tile: write transposed VT[b][h][hd][token], 4 tokens per b64 store.
        const int bb = m0 >> 11;
        const int tok0 = (m0 & 2047) + wr;
        #pragma unroll
        for (int i = 0; i < MROWS; ++i)
            #pragma unroll
            for (int j = 0; j < 4; ++j) {
                int vcol = n0 + wc + j * 16 + l16 - 512;
                int hh = vcol >> 5, d = vcol & 31;
                half4_t p;
                #pragma unroll
                for (int r = 0; r < 4; ++r) p[r] = (_Float16)acc[i][j][r];
                *reinterpret_cast<half4_t*>(
                    VTo + ((size_t)(bb * NHEADS + hh) * HDIM + d) * 2048
                        + tok0 + i * 16 + quad * 4) = p;
            }
    } else {
        float bv[4] = {0.f, 0.f, 0.f, 0.f};
        if (bias != nullptr) {
            #pragma unroll
            for (int j = 0; j < 4; ++j) bv[j] = bias[n0 + wc + j * 16 + l16];
        }
        #pragma unroll
        for (int i = 0; i < MROWS; ++i)
            #pragma unroll
            for (int r = 0; r < 4; ++r) {
                int row = m0 + wr + i * 16 + quad * 4 + r;
                #pragma unroll
                for (int j = 0; j < 4; ++j) {
                    int col = n0 + wc + j * 16 + l16;
                    float v = acc[i][j][r] + bv[j];
                    if (VSPLIT && n0 < 256) v *= QS;  // pre-scale Q for exp2
                    if (OUT_HALF) ((_Float16*)Cv)[(size_t)row * ldc + col] = (_Float16)v;
                    else          ((float*)Cv)[(size_t)row * ldc + col] = v;
                }
            }
    }
}

// ---------------------------------------------------------------------------
// MFMA flash attention v11: asm-load ping-pong with counted vmcnt.
//  - 64 q/wave (v7 shape: 40 MFMA + 64 exp per 8 loads = 2x v10 intensity),
//    key-split x2, 512 blocks, launch_bounds(256,2) (~200 VGPR headroom).
//  - K/V/Q loads are inline-asm global_load_dwordx4: compiler cannot sink,
//    rematerialize, or insert vmcnt(0) (v9/v10 failure mode, VGPR=48/76).
//  - s_waitcnt vmcnt(8): bank B's 8 loads stay in flight across STEP(A) —
//    counted-vmcnt pipeline (T4). sched_barrier(0) fences MFMA hoisting.
// ---------------------------------------------------------------------------

#define GLD(dst, addr) \
    asm volatile("global_load_dwordx4 %0, %1, off" : "=v"(dst) : "v"(addr))
#define WAITV(N) asm volatile("s_waitcnt vmcnt(" #N ")" ::: "memory")
#define SB0 __builtin_amdgcn_sched_barrier(0)

#define LOADASM(P, k0)                                            \
    do {                                                          \
        const _Float16* kp_ = kbase + (size_t)(k0) * 512;         \
        GLD(k##P[0], kp_);                                        \
        GLD(k##P[1], kp_ + (size_t)16 * 512);                     \
        GLD(k##P[2], kp_ + (size_t)32 * 512);                     \
        GLD(k##P[3], kp_ + (size_t)48 * 512);                     \
        const _Float16* vp_ = vbase + (k0);                       \
        GLD(v##P[0], vp_);                                        \
        GLD(v##P[1], vp_ + (size_t)16 * 2048);                    \
        GLD(v##P[2], vp_ + 32);                                   \
        GLD(v##P[3], vp_ + 32 + (size_t)16 * 2048);               \
    } while (0)

// Full 64-key step from bank P: S^T MFMAs -> exp2/pkrtz -> LDS round trip ->
// PV MFMAs + ones-MFMA denominator.
#define STEP(P)                                                                    \
    do {                                                                           \
        half4_t ep[4][4];                                                          \
        _Pragma("unroll")                                                          \
        for (int kb = 0; kb < 4; ++kb)                                             \
            _Pragma("unroll")                                                      \
            for (int g = 0; g < 4; ++g) {                                          \
                float4_t st = __builtin_amdgcn_mfma_f32_16x16x32_f16(              \
                    k##P[kb], qf[g], z, 0, 0, 0);                                  \
                auto lo = __builtin_amdgcn_cvt_pkrtz(fast_exp2(st[0]),             \
                                                     fast_exp2(st[1]));            \
                auto hi = __builtin_amdgcn_cvt_pkrtz(fast_exp2(st[2]),             \
                                                     fast_exp2(st[3]));            \
                ep[kb][g] = (half4_t){(_Float16)lo[0], (_Float16)lo[1],            \
                                      (_Float16)hi[0], (_Float16)hi[1]};           \
            }                                                                      \
        _Pragma("unroll")                                                          \
        for (int s = 0; s < 2; ++s) {                                              \
            _Pragma("unroll")                                                      \
            for (int tt = 0; tt < 2; ++tt)                                         \
                _Pragma("unroll")                                                  \
                for (int g = 0; g < 4; ++g)                                        \
                    *reinterpret_cast<half4_t*>(                                   \
                        esw + (g * 16 + l16) * 40 + tt * 16 + quad * 4) =          \
                        ep[s * 2 + tt][g];                                         \
            _Pragma("unroll")                                                      \
            for (int g = 0; g < 4; ++g) {                                          \
                half8_t ef = *reinterpret_cast<const half8_t*>(                    \
                    esw + (g * 16 + l16) * 40 + quad * 8);                         \
                num[g][0] = __builtin_amdgcn_mfma_f32_16x16x32_f16(                \
                    ef, v##P[s * 2], num[g][0], 0, 0, 0);                          \
                num[g][1] = __builtin_amdgcn_mfma_f32_16x16x32_f16(                \
                    ef, v##P[s * 2 + 1], num[g][1], 0, 0, 0);                      \
                dacc[g] = __builtin_amdgcn_mfma_f32_16x16x32_f16(                  \
                    ef, onef, dacc[g], 0, 0, 0);                                   \
            }                                                                      \
        }                                                                          \
    } while (0)

__global__ __launch_bounds__(256, 2) void attn_v11(const _Float16* __restrict__ qkh,
                                                   const _Float16* __restrict__ VT,
                                                   _Float16* __restrict__ NUM,
                                                   float* __restrict__ DEN) {
    __shared__ alignas(16) _Float16 es[4][64][40];
    // XCD swizzle (bijective, 512 % 8 == 0).
    const int bid = ((blockIdx.x & 7) << 6) | (blockIdx.x >> 3);
    const int kh = bid & 1;
    const int qb = (bid >> 1) & 7;
    const int bh = bid >> 4;
    const int b = bh >> 3, h = bh & 7;
    const int t = threadIdx.x, lane = t & 63, wave = t >> 6;
    const int l16 = lane & 15, quad = lane >> 4;
    const int bN = b * 2048;
    const int q0w = qb * 256 + wave * 64;
    const int kbeg = kh * 1024;

    const _Float16* kbase = qkh + (size_t)(bN + l16) * 512 + 256 + h * HDIM + quad * 8;
    const _Float16* vbase = VT + (size_t)bh * HDIM * 2048 + (size_t)l16 * 2048 + quad * 8;

    float4_t num[4][2];
    #pragma unroll
    for (int g = 0; g < 4; ++g)
        #pragma unroll
        for (int dt = 0; dt < 2; ++dt) num[g][dt] = (float4_t){0.f, 0.f, 0.f, 0.f};
    float4_t dacc[4];
    #pragma unroll
    for (int g = 0; g < 4; ++g) dacc[g] = (float4_t){0.f, 0.f, 0.f, 0.f};

    half8_t onef;
    #pragma unroll
    for (int j = 0; j < 8; ++j) onef[j] = (_Float16)1.0f;

    _Float16* esw = &es[wave][0][0];
    const float4_t z = {0.f, 0.f, 0.f, 0.f};

    // Q fragments via asm loads too: no compiler-tracked VMEM in the hot path,
    // so no hidden vmcnt(0) insertions.
    half8_t qf[4];
    {
        const _Float16* qrow = qkh + (size_t)(bN + q0w + l16) * 512 + h * HDIM + quad * 8;
        GLD(qf[0], qrow);
        GLD(qf[1], qrow + (size_t)16 * 512);
        GLD(qf[2], qrow + (size_t)32 * 512);
        GLD(qf[3], qrow + (size_t)48 * 512);
    }

    half8_t kA[4], vA[4], kB[4], vB[4];
    LOADASM(A, kbeg);                 // outstanding: 4 (qf) + 8 (A)
    for (int k0 = kbeg; k0 < kbeg + 1024; k0 += 128) {
        LOADASM(B, k0 + 64);          // + 8 (B)
        WAITV(8);                     // drain qf + A; B stays in flight
        SB0;
        STEP(A);
        if (k0 + 128 < kbeg + 1024) {
            LOADASM(A, k0 + 128);     // + 8 (A')
            WAITV(8);                 // drain B; A' stays in flight
        } else {
            WAITV(0);                 // tail: drain B
        }
        SB0;
        STEP(B);
    }

    // Store partial numerator (fp16, unnormalized) and partial denom (fp32).
    _Float16* ob = NUM + (size_t)kh * 2097152 + (size_t)(bN + q0w) * DIM + h * HDIM;
    #pragma unroll
    for (int g = 0; g < 4; ++g)
        #pragma unroll
        for (int r = 0; r < 4; ++r) {
            size_t ro = (size_t)(g * 16 + quad * 4 + r) * DIM;
            ob[ro + l16]      = (_Float16)num[g][0][r];
            ob[ro + 16 + l16] = (_Float16)num[g][1][r];
        }
    // dacc[g][r] = denom for q = g*16 + quad*4 + r (replicated over l16).
    if (l16 == 0) {
        #pragma unroll
        for (int g = 0; g < 4; ++g)
            #pragma unroll
            for (int r = 0; r < 4; ++r)
                DEN[kh * 65536 + bh * 2048 + q0w + g * 16 + quad * 4 + r] = dacc[g][r];
    }
}

// ---------------------------------------------------------------------------
// combine: attnh = (NUM0 + NUM1) * rcp(DEN0 + DEN1 + 1e-6), elementwise fp16.
// ---------------------------------------------------------------------------
__global__ __launch_bounds__(256) void combine(const _Float16* __restrict__ NUM,
                                               const float* __restrict__ DEN,
                                               _Float16* __restrict__ attnh) {
    const size_t idx = ((size_t)blockIdx.x * 256 + threadIdx.x) * 8;
    const int row = (int)(idx >> 8);
    const int c = (int)(idx & 255);
    const int b = row >> 11, tok = row & 2047, h = c >> 5;
    const int di = (b * 8 + h) * 2048 + tok;
    float rcp = 1.0f / (DEN[di] + DEN[di + 65536] + 1e-6f);
    half8_t n0 = *reinterpret_cast<const half8_t*>(NUM + idx);
    half8_t n1 = *reinterpret_cast<const half8_t*>(NUM + idx + 2097152);
    *reinterpret_cast<half8_t*>(attnh + idx) = (n0 + n1) * (_Float16)rcp;
}

extern "C" void kernel_launch(void* const* d_in, const int* in_sizes, int n_in,
                              void* d_out, int out_size, void* d_ws, size_t ws_size,
                              hipStream_t stream) {
    const float* x    = (const float*)d_in[0];
    const float* Wqkv = (const float*)d_in[1];
    const float* Wout = (const float*)d_in[2];
    const float* bout = (const float*)d_in[3];
    float* out = (float*)d_out;
    const int M = 8192;

    _Float16* xh    = (_Float16*)d_ws;                 // [8192,256]
    _Float16* WqT   = xh + (size_t)M * DIM;            // [768,256]
    _Float16* WoT   = WqT + 768 * 256;                 // [256,256]
    _Float16* qkh   = WoT + 256 * 256;                 // [8192,512]  (Q|K)
    _Float16* vt    = qkh + (size_t)M * 512;           // [4][8][32][2048] V^T
    _Float16* NUM   = vt + (size_t)32 * HDIM * 2048;   // [2][8192,256] partials
    float*    DEN   = (float*)(NUM + (size_t)2 * M * DIM);  // [2][65536]
    _Float16* attnh = (_Float16*)(DEN + 2 * 65536);    // [8192,256]

    hipLaunchKernelGGL(prep, dim3(1280), dim3(256), 0, stream, x, Wqkv, Wout, xh, WqT, WoT);
    // qkv GEMM: Q (scaled by scale*log2e), K -> qkh (ldc 512); V -> vt transposed.
    hipLaunchKernelGGL((gemm_h<true, true, 2>), dim3(6, 128), dim3(256), 0, stream,
                       xh, WqT, (const float*)nullptr, (void*)qkh, vt, M, 768, DIM, 512);
    // attention: 512 blocks (2/CU), 64 q/wave, key-split x2, asm prefetch.
    hipLaunchKernelGGL(attn_v11, dim3(512), dim3(256), 0, stream, qkh, vt, NUM, DEN);
    // combine partials -> attnh
    hipLaunchKernelGGL(combine, dim3(1024), dim3(256), 0, stream, NUM, DEN, attnh);
    // out = attnh @ Wout + bout (fp32 out): 64-row M-tiles -> 256 balanced blocks.
    hipLaunchKernelGGL((gemm_h<false, false, 2>), dim3(2, 128), dim3(256), 0, stream,
                       attnh, WoT, bout, (void*)out, (_Float16*)nullptr, M, DIM, DIM, DIM);
}